// Round 1
// baseline (511.367 us; speedup 1.0000x reference)
//
#include <hip/hip_runtime.h>
#include <stdint.h>

#define LL 512
#define DD 64

typedef __attribute__((ext_vector_type(8))) short bf16x8;
typedef __attribute__((ext_vector_type(4))) float f32x4;

#define MFMA16(a, b, c) __builtin_amdgcn_mfma_f32_16x16x32_bf16((a), (b), (c), 0, 0, 0)

__device__ __forceinline__ float bf2f(unsigned short u) {
    union { unsigned int i; float f; } v; v.i = ((unsigned int)u) << 16; return v.f;
}
__device__ __forceinline__ unsigned short f2bf(float f) {
    union { float f; unsigned int i; } v; v.f = f;
    unsigned int i = v.i;
    return (unsigned short)((i + 0x7FFFu + ((i >> 16) & 1u)) >> 16);  // RNE
}
__device__ __forceinline__ float sigm(float x) { return 1.0f / (1.0f + __expf(-x)); }

// ---------------------------------------------------------------- prep ------
__global__ void prep_w(const float* __restrict__ Wl, const float* __restrict__ Wr,
                       const float* __restrict__ Wlg, const float* __restrict__ Wrg,
                       const float* __restrict__ Wog, const float* __restrict__ Wout,
                       unsigned short* __restrict__ Wcat, unsigned short* __restrict__ WoutB) {
    int t = threadIdx.x + blockIdx.x * blockDim.x;
    int stride = blockDim.x * gridDim.x;
    for (int idx = t; idx < 320 * 64; idx += stride) {
        int row = idx >> 6, col = idx & 63;
        int sec = row >> 6, r = row & 63;
        float v;
        switch (sec) {
            case 0:  v = Wl[r * 64 + col];  break;
            case 1:  v = Wlg[r * 64 + col]; break;
            case 2:  v = Wr[r * 64 + col];  break;
            case 3:  v = Wrg[r * 64 + col]; break;
            default: v = Wog[r * 64 + col]; break;
        }
        Wcat[idx] = f2bf(v);
    }
    for (int idx = t; idx < 64 * 64; idx += stride) WoutB[idx] = f2bf(Wout[idx]);
}

// ------------------------------------------------- k1: LN + proj + gates ----
// block: (b, irow, 128-chunk of second index). 256 threads = 4 waves.
__launch_bounds__(256)
__global__ void k1_proj(const float* __restrict__ pair, const float* __restrict__ torsion,
                        const float* __restrict__ ln_g, const float* __restrict__ ln_b,
                        const float* __restrict__ blg, const float* __restrict__ brg,
                        const float* __restrict__ bog, const float* __restrict__ Wt,
                        const float* __restrict__ bt, const unsigned short* __restrict__ Wcat,
                        unsigned short* __restrict__ At, unsigned short* __restrict__ Bt,
                        unsigned short* __restrict__ G) {
    const int bb = blockIdx.z, irow = blockIdx.y, c0 = blockIdx.x * 128;
    const int t = threadIdx.x, w = t >> 6, lane = t & 63;
    __shared__ unsigned short zs[128][72];   // pitch 144B: 16B-aligned rows, 2-way banks

    float tww;
    {
        float acc = bt[0];
        #pragma unroll
        for (int n = 0; n < 6; ++n) acc += torsion[(bb * LL + irow) * 6 + n] * Wt[n];
        tww = sigm(acc);
    }

    const float lg = ln_g[lane], lb = ln_b[lane];
    const float* prow = pair + ((size_t)(bb * LL + irow) * LL + c0) * DD;
    for (int r = w; r < 128; r += 4) {
        float v = prow[r * DD + lane];
        float s = v, s2 = v * v;
        #pragma unroll
        for (int off = 32; off > 0; off >>= 1) {
            s += __shfl_xor(s, off);
            s2 += __shfl_xor(s2, off);
        }
        float m = s * 0.015625f;
        float var = s2 * 0.015625f - m * m;
        float rstd = rsqrtf(var + 1e-5f);
        zs[r][lane] = f2bf((v - m) * rstd * lg + lb);
    }
    __syncthreads();

    const int rsel = lane & 15, koff = lane >> 4;
    #pragma unroll
    for (int mh = 0; mh < 2; ++mh) {
        const int mi = 2 * w + mh;
        bf16x8 a0 = *(const bf16x8*)&zs[mi * 16 + rsel][koff * 8];
        bf16x8 a1 = *(const bf16x8*)&zs[mi * 16 + rsel][32 + koff * 8];
        #pragma unroll
        for (int n = 0; n < 4; ++n) {
            const int col = n * 16 + rsel;   // output channel d
            f32x4 pl = {0.f, 0.f, 0.f, 0.f}, plg = pl, pr = pl, prg = pl, pog = pl;
            const unsigned short* w0 = Wcat + (size_t)(0 * 64 + col) * 64;
            const unsigned short* w1 = Wcat + (size_t)(1 * 64 + col) * 64;
            const unsigned short* w2 = Wcat + (size_t)(2 * 64 + col) * 64;
            const unsigned short* w3 = Wcat + (size_t)(3 * 64 + col) * 64;
            const unsigned short* w4 = Wcat + (size_t)(4 * 64 + col) * 64;
            pl  = MFMA16(a0, *(const bf16x8*)&w0[koff * 8], pl);
            pl  = MFMA16(a1, *(const bf16x8*)&w0[32 + koff * 8], pl);
            plg = MFMA16(a0, *(const bf16x8*)&w1[koff * 8], plg);
            plg = MFMA16(a1, *(const bf16x8*)&w1[32 + koff * 8], plg);
            pr  = MFMA16(a0, *(const bf16x8*)&w2[koff * 8], pr);
            pr  = MFMA16(a1, *(const bf16x8*)&w2[32 + koff * 8], pr);
            prg = MFMA16(a0, *(const bf16x8*)&w3[koff * 8], prg);
            prg = MFMA16(a1, *(const bf16x8*)&w3[32 + koff * 8], prg);
            pog = MFMA16(a0, *(const bf16x8*)&w4[koff * 8], pog);
            pog = MFMA16(a1, *(const bf16x8*)&w4[32 + koff * 8], pog);

            const float vblg = blg[col], vbrg = brg[col], vbog = bog[col];
            unsigned short aw4[4], bm4[4], g4[4];
            #pragma unroll
            for (int r = 0; r < 4; ++r) {
                float av = pl[r] * sigm(plg[r] + vblg) * tww;
                float bv = pr[r] * sigm(prg[r] + vbrg);
                float gv = sigm(pog[r] + vbog);
                aw4[r] = f2bf(av); bm4[r] = f2bf(bv); g4[r] = f2bf(gv);
            }
            const int crow = mi * 16 + koff * 4;   // 4 consecutive positions
            size_t aidx = ((size_t)(bb * 64 + col) * LL + irow) * LL + (c0 + crow);
            *(ushort4*)&At[aidx] = make_ushort4(aw4[0], aw4[1], aw4[2], aw4[3]);
            *(ushort4*)&Bt[aidx] = make_ushort4(bm4[0], bm4[1], bm4[2], bm4[3]);
            size_t gbase = ((size_t)(bb * LL + irow) * LL + (c0 + crow)) * DD + col;
            #pragma unroll
            for (int r = 0; r < 4; ++r) G[gbase + (size_t)r * DD] = g4[r];
        }
    }
}

// ------------------------------------------ k2: batched plane GEMM (AB^T) ---
// grid: x = 16 tiles (4x4 of 128x128), y = 128 planes. 256 threads = 4 waves.
__launch_bounds__(256)
__global__ void k2_gemm(const unsigned short* __restrict__ At,
                        const unsigned short* __restrict__ Bt,
                        unsigned short* __restrict__ Xt) {
    const int p = blockIdx.y;
    const int i0 = (blockIdx.x >> 2) * 128, j0 = (blockIdx.x & 3) * 128;
    const unsigned short* Ap = At + (size_t)p * LL * LL + (size_t)i0 * LL;
    const unsigned short* Bp = Bt + (size_t)p * LL * LL + (size_t)j0 * LL;
    __shared__ unsigned short As[128][40], Bs[128][40];   // pitch 80B (16B-aligned, ~2-way banks)
    __shared__ unsigned short Cs[128][136];               // pitch 272B (16B-aligned)
    const int t = threadIdx.x, lane = t & 63, w = t >> 6;
    const int rsel = lane & 15, koff = lane >> 4;
    const int wm = w >> 1, wn = w & 1;

    f32x4 acc[4][4];
    #pragma unroll
    for (int i = 0; i < 4; ++i)
        #pragma unroll
        for (int j = 0; j < 4; ++j) acc[i][j] = (f32x4){0.f, 0.f, 0.f, 0.f};

    const int srow0 = t >> 2, skq = t & 3;
    uint4 ra[2], rb[2];
    #pragma unroll
    for (int q = 0; q < 2; ++q) {
        int row = srow0 + q * 64;
        ra[q] = *(const uint4*)&Ap[(size_t)row * LL + skq * 8];
        rb[q] = *(const uint4*)&Bp[(size_t)row * LL + skq * 8];
    }
    for (int k0 = 0; k0 < LL; k0 += 32) {
        #pragma unroll
        for (int q = 0; q < 2; ++q) {
            int row = srow0 + q * 64;
            *(uint4*)&As[row][skq * 8] = ra[q];
            *(uint4*)&Bs[row][skq * 8] = rb[q];
        }
        __syncthreads();
        if (k0 + 32 < LL) {
            #pragma unroll
            for (int q = 0; q < 2; ++q) {
                int row = srow0 + q * 64;
                ra[q] = *(const uint4*)&Ap[(size_t)row * LL + (k0 + 32) + skq * 8];
                rb[q] = *(const uint4*)&Bp[(size_t)row * LL + (k0 + 32) + skq * 8];
            }
        }
        bf16x8 af[4], bfr[4];
        #pragma unroll
        for (int mi = 0; mi < 4; ++mi)
            af[mi] = *(const bf16x8*)&As[wm * 64 + mi * 16 + rsel][koff * 8];
        #pragma unroll
        for (int ni = 0; ni < 4; ++ni)
            bfr[ni] = *(const bf16x8*)&Bs[wn * 64 + ni * 16 + rsel][koff * 8];
        #pragma unroll
        for (int mi = 0; mi < 4; ++mi)
            #pragma unroll
            for (int ni = 0; ni < 4; ++ni)
                acc[mi][ni] = MFMA16(af[mi], bfr[ni], acc[mi][ni]);
        __syncthreads();
    }
    const float s = 1.0f / (sqrtf((float)LL) + 1e-8f);
    #pragma unroll
    for (int mi = 0; mi < 4; ++mi)
        #pragma unroll
        for (int ni = 0; ni < 4; ++ni)
            #pragma unroll
            for (int r = 0; r < 4; ++r)
                Cs[wm * 64 + mi * 16 + koff * 4 + r][wn * 64 + ni * 16 + rsel] =
                    f2bf(acc[mi][ni][r] * s);
    __syncthreads();
    #pragma unroll
    for (int it = 0; it < 8; ++it) {
        int row = it * 16 + (t >> 4), colc = (t & 15) * 8;
        uint4 v = *(const uint4*)&Cs[row][colc];
        *(uint4*)&Xt[((size_t)p * LL + i0 + row) * LL + j0 + colc] = v;
    }
}

// ----------------------------- k3: transpose + LN + out-proj + gate + res ---
__launch_bounds__(256)
__global__ void k3_out(const unsigned short* __restrict__ Xt, const unsigned short* __restrict__ G,
                       const float* __restrict__ pairIn, const unsigned short* __restrict__ WoutB,
                       const float* __restrict__ lno_g, const float* __restrict__ lno_b,
                       const float* __restrict__ bout, float* __restrict__ out) {
    const int bb = blockIdx.z, irow = blockIdx.y, c0 = blockIdx.x * 128;
    const int t = threadIdx.x, w = t >> 6, lane = t & 63;
    __shared__ unsigned short x1[64][128];   // [d][c] staging, reused as o_lds [128][64]
    __shared__ unsigned short x2[128][72];   // [c][d] transposed

    #pragma unroll
    for (int q = 0; q < 4; ++q) {
        int idx = t + q * 256, d = idx >> 4, c8 = idx & 15;
        uint4 v = *(const uint4*)&Xt[((size_t)(bb * 64 + d) * LL + irow) * LL + c0 + c8 * 8];
        *(uint4*)&x1[d][c8 * 8] = v;
    }
    __syncthreads();
    {
        const int c = t & 127, half = t >> 7;
        unsigned short tmp[32];
        #pragma unroll
        for (int dd = 0; dd < 32; ++dd) tmp[dd] = x1[half * 32 + dd][c];
        #pragma unroll
        for (int q = 0; q < 4; ++q)
            *(uint4*)&x2[c][half * 32 + q * 8] = *(const uint4*)&tmp[q * 8];
    }
    __syncthreads();

    const float lg = lno_g[lane], lb = lno_b[lane];
    for (int r = w; r < 128; r += 4) {
        float v = bf2f(x2[r][lane]);
        float s = v, s2 = v * v;
        #pragma unroll
        for (int off = 32; off > 0; off >>= 1) {
            s += __shfl_xor(s, off);
            s2 += __shfl_xor(s2, off);
        }
        float m = s * 0.015625f;
        float var = s2 * 0.015625f - m * m;
        float rstd = rsqrtf(var + 1e-5f);
        x2[r][lane] = f2bf((v - m) * rstd * lg + lb);
    }
    __syncthreads();

    unsigned short* o_lds = &x1[0][0];   // [128][64]
    const int rsel = lane & 15, koff = lane >> 4;
    #pragma unroll
    for (int mh = 0; mh < 2; ++mh) {
        const int mi = 2 * w + mh;
        bf16x8 a0 = *(const bf16x8*)&x2[mi * 16 + rsel][koff * 8];
        bf16x8 a1 = *(const bf16x8*)&x2[mi * 16 + rsel][32 + koff * 8];
        #pragma unroll
        for (int n = 0; n < 4; ++n) {
            f32x4 pacc = {0.f, 0.f, 0.f, 0.f};
            const unsigned short* wrow = WoutB + (size_t)(n * 16 + rsel) * 64;
            pacc = MFMA16(a0, *(const bf16x8*)&wrow[koff * 8], pacc);
            pacc = MFMA16(a1, *(const bf16x8*)&wrow[32 + koff * 8], pacc);
            const float bo = bout[n * 16 + rsel];
            #pragma unroll
            for (int r = 0; r < 4; ++r)
                o_lds[(mi * 16 + koff * 4 + r) * 64 + n * 16 + rsel] = f2bf(pacc[r] + bo);
        }
    }
    __syncthreads();

    #pragma unroll
    for (int q = 0; q < 4; ++q) {
        int e = q * 2048 + t * 8;
        int c = e >> 6, o = e & 63;
        size_t pos = (size_t)(bb * LL + irow) * LL + c0 + c;
        uint4 ov = *(const uint4*)&o_lds[c * 64 + o];
        uint4 gv = *(const uint4*)&G[pos * DD + o];
        const unsigned short* ovp = (const unsigned short*)&ov;
        const unsigned short* gvp = (const unsigned short*)&gv;
        float4 p0 = *(const float4*)&pairIn[pos * DD + o];
        float4 p1 = *(const float4*)&pairIn[pos * DD + o + 4];
        float4 r0, r1;
        r0.x = p0.x + bf2f(ovp[0]) * bf2f(gvp[0]);
        r0.y = p0.y + bf2f(ovp[1]) * bf2f(gvp[1]);
        r0.z = p0.z + bf2f(ovp[2]) * bf2f(gvp[2]);
        r0.w = p0.w + bf2f(ovp[3]) * bf2f(gvp[3]);
        r1.x = p1.x + bf2f(ovp[4]) * bf2f(gvp[4]);
        r1.y = p1.y + bf2f(ovp[5]) * bf2f(gvp[5]);
        r1.z = p1.z + bf2f(ovp[6]) * bf2f(gvp[6]);
        r1.w = p1.w + bf2f(ovp[7]) * bf2f(gvp[7]);
        *(float4*)&out[pos * DD + o] = r0;
        *(float4*)&out[pos * DD + o + 4] = r1;
    }
}

// ----------------------------------------------------------------- launch ---
extern "C" void kernel_launch(void* const* d_in, const int* in_sizes, int n_in,
                              void* d_out, int out_size, void* d_ws, size_t ws_size,
                              hipStream_t stream) {
    const float* pair    = (const float*)d_in[0];
    const float* torsion = (const float*)d_in[1];
    const float* ln_g    = (const float*)d_in[2];
    const float* ln_b    = (const float*)d_in[3];
    const float* Wl      = (const float*)d_in[4];
    const float* Wr      = (const float*)d_in[5];
    const float* Wlg     = (const float*)d_in[6];
    const float* blg     = (const float*)d_in[7];
    const float* Wrg     = (const float*)d_in[8];
    const float* brg     = (const float*)d_in[9];
    const float* Wog     = (const float*)d_in[10];
    const float* bog     = (const float*)d_in[11];
    const float* Wout    = (const float*)d_in[12];
    const float* bout    = (const float*)d_in[13];
    const float* lno_g   = (const float*)d_in[14];
    const float* lno_b   = (const float*)d_in[15];
    const float* Wt      = (const float*)d_in[16];
    const float* bt      = (const float*)d_in[17];
    float* outp = (float*)d_out;

    const size_t PLANE_B = (size_t)128 * LL * LL * 2;   // 64 MiB per block
    const size_t need = 4 * PLANE_B + (320 * 64 + 64 * 64) * 2;
    if (ws_size < need) return;   // insufficient workspace; fail validation cleanly

    char* ws = (char*)d_ws;
    unsigned short* At    = (unsigned short*)(ws);
    unsigned short* Bt_   = (unsigned short*)(ws + PLANE_B);
    unsigned short* G     = (unsigned short*)(ws + 2 * PLANE_B);
    unsigned short* Xt    = (unsigned short*)(ws + 3 * PLANE_B);
    unsigned short* Wcat  = (unsigned short*)(ws + 4 * PLANE_B);
    unsigned short* WoutB = Wcat + 320 * 64;

    prep_w<<<dim3(40), dim3(256), 0, stream>>>(Wl, Wr, Wlg, Wrg, Wog, Wout, Wcat, WoutB);
    k1_proj<<<dim3(4, LL, 2), dim3(256), 0, stream>>>(pair, torsion, ln_g, ln_b, blg, brg,
                                                      bog, Wt, bt, Wcat, At, Bt_, G);
    k2_gemm<<<dim3(16, 128), dim3(256), 0, stream>>>(At, Bt_, Xt);
    k3_out<<<dim3(4, LL, 2), dim3(256), 0, stream>>>(Xt, G, pair, WoutB, lno_g, lno_b, bout, outp);
}